// Round 19
// baseline (164.258 us; speedup 1.0000x reference)
//
#include <hip/hip_runtime.h>

#define PP 256
#define SS 256
#define CORE_ 192
#define HH 256
#define NHEAD 8
#define DD 32

typedef __attribute__((ext_vector_type(4))) float f32x4;
typedef __attribute__((ext_vector_type(8))) short s8v;
typedef __attribute__((ext_vector_type(4))) short s4v;

__device__ __forceinline__ unsigned short f2bf(float f) {
    union { float f; unsigned int i; } c; c.f = f;
    unsigned int i = c.i;
    return (unsigned short)((i + 0x7fffu + ((i >> 16) & 1u)) >> 16);
}

// async global->LDS 16B DMA; lds base must be wave-uniform (HW adds lane*16)
__device__ __forceinline__ void gload16(const unsigned short* g, unsigned short* l) {
    __builtin_amdgcn_global_load_lds(
        (const __attribute__((address_space(1))) void*)g,
        (__attribute__((address_space(3))) void*)l, 16, 0, 0);
}

// 16B-chunk XOR swizzle (involution) for [rows][32-short] tiles; 0-conflict (r3/r6).
#define SW(row, chunk) ((chunk) ^ (((row) >> 1) & 3))
// Vt swizzle (r12): 2-way on reads (d = nt*16+c0), 4-distinct on writes (d = dw*8+e)
#define SVT(d) ((((d) >> 1) & 3) ^ (((d) & 8) >> 1) ^ (((d) & 16) >> 3))

// ---------------- K0: fused pre-pass: x cast + weight/bias pack --------
__global__ __launch_bounds__(256) void k_pre(
    const float* __restrict__ x,
    const float* __restrict__ Wq, const float* __restrict__ Wk,
    const float* __restrict__ Wv, const float* __restrict__ Wo,
    const float* __restrict__ bq, const float* __restrict__ bk,
    const float* __restrict__ bv,
    unsigned short* __restrict__ xb,
    unsigned short* __restrict__ Wb, float* __restrict__ bb) {
    int bid = blockIdx.x, tid = threadIdx.x;
    if (bid < 6144) {
        size_t i = ((size_t)bid * 256 + tid) * 8;
        float4 a = *(const float4*)(x + i);
        float4 b = *(const float4*)(x + i + 4);
        s8v w;
        w[0] = (short)f2bf(a.x); w[1] = (short)f2bf(a.y);
        w[2] = (short)f2bf(a.z); w[3] = (short)f2bf(a.w);
        w[4] = (short)f2bf(b.x); w[5] = (short)f2bf(b.y);
        w[6] = (short)f2bf(b.z); w[7] = (short)f2bf(b.w);
        *(s8v*)(xb + i) = w;
        return;
    }
    if (bid >= 6272) {
        int which = bid - 6272;
        const float* b = which == 0 ? bq : which == 1 ? bk : bv;
        bb[which * 256 + tid] = b[tid];
        return;
    }
    int c = (bid - 6144) * 256 + tid;   // chunk 0..32767
    int row = c >> 5;                   // 0..1023
    int within = c & 31;
    int w = within >> 2, sl = within & 3;
    const float* src = row < 256 ? Wq : row < 512 ? Wk : row < 768 ? Wv : Wo;
    const float* sp = src + (size_t)(row & 255) * 256 + w * 32 + SW(row, sl) * 8;
    float4 a = *(const float4*)sp;
    float4 b4 = *(const float4*)(sp + 4);
    s8v wv;
    wv[0] = (short)f2bf(a.x); wv[1] = (short)f2bf(a.y);
    wv[2] = (short)f2bf(a.z); wv[3] = (short)f2bf(a.w);
    wv[4] = (short)f2bf(b4.x); wv[5] = (short)f2bf(b4.y);
    wv[6] = (short)f2bf(b4.z); wv[7] = (short)f2bf(b4.w);
    *(s8v*)(Wb + (size_t)row * 256 + w * 32 + sl * 8) = wv;
}

// ---------------- K1: QKV projection (M=128/wave, BK=64, 4 waves) ------
// grid (P, 2 mt of 128 rows, 3 ng), block 256 (4 waves = 4 N-quarters).
// Each wave computes ALL 128 m-rows (acc[8][4]) -> 64 MFMA per drain,
// half the drains of r13. Same 0-conflict SW sub-tile layouts.
__global__ __launch_bounds__(256) void k_qkv(
    const unsigned short* __restrict__ xb, const int* __restrict__ pidx,
    const unsigned short* __restrict__ Wb, const float* __restrict__ bb,
    unsigned short* __restrict__ qkv) {
    int p = blockIdx.x, mt = blockIdx.y, ng = blockIdx.z;
    __shared__ unsigned short As[2][128][32];   // 16KB
    __shared__ unsigned short Bs[2][256][32];   // 32KB
    int tid = threadIdx.x;
    int wave = tid >> 6, lane = tid & 63;
    int g = lane >> 4, c0 = lane & 15;
    f32x4 acc[8][4] = {};
    int arow = tid >> 1, akk = tid & 1;        // 128 rows x 2 kk-halves
    int node = pidx[p * SS + mt * 128 + arow];
    const unsigned short* asrc = xb + (size_t)node * HH + akk * 32;
    const unsigned short* wsrc = Wb + (size_t)ng * 256 * 256;
    // ng==0,mt==1: rows 128..255; only 128..191 (m2<4) consumed
    int m2max = (ng == 0 && mt == 1) ? 4 : 8;

    s8v av[4];
#pragma unroll
    for (int j = 0; j < 4; ++j) av[j] = *(const s8v*)(asrc + j * 8);
#pragma unroll
    for (int ks = 0; ks < 4; ++ks) {
        int k0 = ks * 64;
        // B: 2 sub-tiles x 1024 chunks, async DMA (pre-swizzled source)
#pragma unroll
        for (int kk = 0; kk < 2; ++kk)
#pragma unroll
            for (int j = 0; j < 4; ++j) {
                int chunk = j * 256 + wave * 64 + lane;
                int row = chunk >> 2, c8 = chunk & 3;
                gload16(wsrc + (size_t)row * 256 + k0 + kk * 32 + c8 * 8,
                        &Bs[kk][0][0] + (size_t)(j * 256 + wave * 64) * 8);
            }
        // A: thread owns (row, kk-half): 4 chunk writes, SW layout
#pragma unroll
        for (int j = 0; j < 4; ++j)
            *(s8v*)&As[akk][arow][SW(arow, j) * 8] = av[j];
        if (ks < 3)
#pragma unroll
            for (int j = 0; j < 4; ++j)
                av[j] = *(const s8v*)(asrc + k0 + 64 + j * 8);
        __syncthreads();
        s8v bfv[4][2];
#pragma unroll
        for (int nt = 0; nt < 4; ++nt) {
            int r = wave * 64 + nt * 16 + c0;
#pragma unroll
            for (int kk = 0; kk < 2; ++kk)
                bfv[nt][kk] = *(const s8v*)&Bs[kk][r][SW(r, g) * 8];
        }
#pragma unroll
        for (int m2 = 0; m2 < 8; ++m2) {
            if (m2 >= m2max) continue;
            int r = m2 * 16 + c0;
            s8v af0 = *(const s8v*)&As[0][r][SW(r, g) * 8];
            s8v af1 = *(const s8v*)&As[1][r][SW(r, g) * 8];
#pragma unroll
            for (int nt = 0; nt < 4; ++nt) {
                acc[m2][nt] = __builtin_amdgcn_mfma_f32_16x16x32_bf16(
                    af0, bfv[nt][0], acc[m2][nt], 0, 0, 0);
                acc[m2][nt] = __builtin_amdgcn_mfma_f32_16x16x32_bf16(
                    af1, bfv[nt][1], acc[m2][nt], 0, 0, 0);
            }
        }
        __syncthreads();
    }
    // epilogue: +bias; Q pre-scaled by log2(e)/sqrt(32); K stored swcol'd
    float sc = (ng == 0) ? 0.2550348792930095f : 1.0f;
#pragma unroll
    for (int nt = 0; nt < 4; ++nt) {
        int ncol = wave * 64 + nt * 16 + c0;
        float bv_ = bb[ng * 256 + ncol];
#pragma unroll
        for (int m2 = 0; m2 < 8; ++m2) {
            if (m2 >= m2max) continue;
#pragma unroll
            for (int r = 0; r < 4; ++r) {
                int srow = mt * 128 + m2 * 16 + g * 4 + r;
                int sc_col = ncol;
                if (ng == 1) {  // store K chunk-swizzled so DMA+SW read works
                    sc_col = (ncol & ~31) |
                             ((((ncol >> 3) & 3) ^ ((srow >> 1) & 3)) << 3) |
                             (ncol & 7);
                }
                qkv[((size_t)p * SS + srow) * 768 + ng * 256 + sc_col] =
                    f2bf((acc[m2][nt][r] + bv_) * sc);
            }
        }
    }
}

// ---------------- K2: attention (swapped QK^T, in-reg P, setprio) ------
__global__ __launch_bounds__(256) void k_attn(
    const unsigned short* __restrict__ qkv, unsigned short* __restrict__ att) {
    int p = blockIdx.x, h = blockIdx.y;
    __shared__ unsigned short Ks[256][32];
    __shared__ unsigned short Vt[32][256];
    int tid = threadIdx.x;
    int wave = tid >> 6, lane = tid & 63;
    int g = lane >> 4, c0 = lane & 15;

#pragma unroll
    for (int j = 0; j < 4; ++j) {
        int chunk = j * 256 + wave * 64 + lane;
        int row = chunk >> 2, c8 = chunk & 3;
        gload16(qkv + ((size_t)p * SS + row) * 768 + 256 + h * DD + c8 * 8,
                &Ks[0][0] + (size_t)(j * 256 + wave * 64) * 8);
    }
    {
        int dw = tid & 3, jb = tid >> 2;       // jb 0..63
        int j0 = jb * 4;
        const unsigned short* vbase =
            qkv + ((size_t)p * SS + j0) * 768 + 512 + h * DD + dw * 8;
        s8v r0 = *(const s8v*)(vbase);
        s8v r1 = *(const s8v*)(vbase + 768);
        s8v r2 = *(const s8v*)(vbase + 1536);
        s8v r3 = *(const s8v*)(vbase + 2304);
        int cj = (j0 >> 5) * 4 + ((j0 >> 2) & 3);   // slot chunk (0..31)
        int jo = ((j0 >> 4) & 1) * 4;               // offset within chunk {0,4}
#pragma unroll
        for (int e = 0; e < 8; ++e) {
            int d = dw * 8 + e;
            s4v w4;
            w4[0] = r0[e]; w4[1] = r1[e]; w4[2] = r2[e]; w4[3] = r3[e];
            *(s4v*)&Vt[d][((cj ^ SVT(d)) << 3) + jo] = w4;
        }
    }
    __syncthreads();

    for (int mi = 0; mi < 3; ++mi) {
        int q0 = (wave * 3 + mi) * 16;
        s8v qa = *(const s8v*)(qkv + ((size_t)p * SS + q0 + c0) * 768 + h * DD + g * 8);
        unsigned int plo[16], phi[16];
        float sum = 0.f;
        __builtin_amdgcn_s_setprio(1);     // favor this wave while MFMA-heavy
#pragma unroll
        for (int jt = 0; jt < 16; ++jt) {
            int row = jt * 16 + c0;
            s8v kf = *(const s8v*)&Ks[row][SW(row, g) * 8];
            f32x4 s = __builtin_amdgcn_mfma_f32_16x16x32_bf16(
                kf, qa, f32x4{0.f, 0.f, 0.f, 0.f}, 0, 0, 0);
            float e0 = exp2f(s[0]), e1 = exp2f(s[1]);
            float e2 = exp2f(s[2]), e3 = exp2f(s[3]);
            sum += (e0 + e1) + (e2 + e3);
            unsigned int lo, hi;
            asm("v_cvt_pk_bf16_f32 %0, %1, %2" : "=v"(lo) : "v"(e0), "v"(e1));
            asm("v_cvt_pk_bf16_f32 %0, %1, %2" : "=v"(hi) : "v"(e2), "v"(e3));
            plo[jt] = lo; phi[jt] = hi;
        }
        __builtin_amdgcn_s_setprio(0);
        sum += __shfl_xor(sum, 16, 64);
        sum += __shfl_xor(sum, 32, 64);
        float linv = 1.f / sum;        // for q = q0 + c0
        float lrow[4];
#pragma unroll
        for (int r = 0; r < 4; ++r) lrow[r] = __shfl(linv, g * 4 + r, 64);

        f32x4 oacc[2] = {f32x4{0.f, 0.f, 0.f, 0.f}, f32x4{0.f, 0.f, 0.f, 0.f}};
        __builtin_amdgcn_s_setprio(1);
#pragma unroll
        for (int ks = 0; ks < 8; ++ks) {
            union { unsigned int u[4]; s8v v; } pa;
            pa.u[0] = plo[2 * ks];     pa.u[1] = phi[2 * ks];
            pa.u[2] = plo[2 * ks + 1]; pa.u[3] = phi[2 * ks + 1];
#pragma unroll
            for (int nt = 0; nt < 2; ++nt) {
                int d = nt * 16 + c0;
                s8v vb = *(const s8v*)&Vt[d][(((ks * 4 + g) ^ SVT(d)) << 3)];
                oacc[nt] = __builtin_amdgcn_mfma_f32_16x16x32_bf16(
                    pa.v, vb, oacc[nt], 0, 0, 0);
            }
        }
        __builtin_amdgcn_s_setprio(0);
#pragma unroll
        for (int nt = 0; nt < 2; ++nt)
#pragma unroll
            for (int r = 0; r < 4; ++r) {
                int qq = g * 4 + r;
                att[((size_t)p * CORE_ + q0 + qq) * HH + h * DD + nt * 16 + c0] =
                    f2bf(oacc[nt][r] * lrow[r]);
            }
    }
}

// ---------------- K3: out-proj + residual + LayerNorm (r15, BK=64) -----
__global__ __launch_bounds__(256) void k_out(
    const unsigned short* __restrict__ att, const float* __restrict__ x,
    const unsigned short* __restrict__ Wb, const float* __restrict__ bo,
    const float* __restrict__ ln_g, const float* __restrict__ ln_b,
    float* __restrict__ out) {
    int p = blockIdx.x, mb = blockIdx.y;
    __shared__ unsigned short As[2][64][32];
    __shared__ unsigned short Bs[2][256][32];
    int tid = threadIdx.x;
    int wave = tid >> 6, lane = tid & 63;
    int g = lane >> 4, c0 = lane & 15;
    f32x4 acc[16] = {};
    int arow = tid >> 2, aseg = tid & 3;
    const unsigned short* asrc =
        att + ((size_t)p * CORE_ + mb * 64 + arow) * HH + aseg * 8;

    s8v av0 = *(const s8v*)(asrc);
    s8v av1 = *(const s8v*)(asrc + 32);
#pragma unroll
    for (int ks = 0; ks < 4; ++ks) {
        int k0 = ks * 64;
#pragma unroll
        for (int kk = 0; kk < 2; ++kk)
#pragma unroll
            for (int j = 0; j < 4; ++j) {
                int chunk = j * 256 + wave * 64 + lane;
                int row = chunk >> 2, c8 = chunk & 3;
                gload16(Wb + (size_t)(768 + row) * 256 + k0 + kk * 32 + c8 * 8,
                        &Bs[kk][0][0] + (size_t)(j * 256 + wave * 64) * 8);
            }
        *(s8v*)&As[0][arow][SW(arow, aseg) * 8] = av0;
        *(s8v*)&As[1][arow][SW(arow, aseg) * 8] = av1;
        if (ks < 3) {
            av0 = *(const s8v*)(asrc + k0 + 64);
            av1 = *(const s8v*)(asrc + k0 + 96);
        }
        __syncthreads();
        int ar = wave * 16 + c0;
        s8v af0 = *(const s8v*)&As[0][ar][SW(ar, g) * 8];
        s8v af1 = *(const s8v*)&As[1][ar][SW(ar, g) * 8];
#pragma unroll
        for (int nt = 0; nt < 16; ++nt) {
            int r = nt * 16 + c0;
            s8v b0 = *(const s8v*)&Bs[0][r][SW(r, g) * 8];
            s8v b1 = *(const s8v*)&Bs[1][r][SW(r, g) * 8];
            acc[nt] = __builtin_amdgcn_mfma_f32_16x16x32_bf16(af0, b0, acc[nt], 0, 0, 0);
            acc[nt] = __builtin_amdgcn_mfma_f32_16x16x32_bf16(af1, b1, acc[nt], 0, 0, 0);
        }
        __syncthreads();
    }
    int srow0 = mb * 64 + wave * 16 + g * 4;
    float sum[4] = {0, 0, 0, 0}, ssq[4] = {0, 0, 0, 0};
#pragma unroll
    for (int nt = 0; nt < 16; ++nt) {
        int col = nt * 16 + c0;
        float bov = bo[col];
#pragma unroll
        for (int r = 0; r < 4; ++r) {
            size_t node = (size_t)p * CORE_ + srow0 + r;
            float v = acc[nt][r] + bov + x[node * HH + col];
            acc[nt][r] = v;
            sum[r] += v; ssq[r] += v * v;
        }
    }
#pragma unroll
    for (int off = 1; off < 16; off <<= 1) {
#pragma unroll
        for (int r = 0; r < 4; ++r) {
            sum[r] += __shfl_xor(sum[r], off, 64);
            ssq[r] += __shfl_xor(ssq[r], off, 64);
        }
    }
#pragma unroll
    for (int r = 0; r < 4; ++r) {
        float mu = sum[r] * (1.f / HH);
        float var = ssq[r] * (1.f / HH) - mu * mu;
        float rstd = rsqrtf(var + 1e-5f);
        size_t node = (size_t)p * CORE_ + srow0 + r;
#pragma unroll
        for (int nt = 0; nt < 16; ++nt) {
            int col = nt * 16 + c0;
            out[node * HH + col] = (acc[nt][r] - mu) * rstd * ln_g[col] + ln_b[col];
        }
    }
}

extern "C" void kernel_launch(void* const* d_in, const int* in_sizes, int n_in,
                              void* d_out, int out_size, void* d_ws, size_t ws_size,
                              hipStream_t stream) {
    const float* x   = (const float*)d_in[0];
    const int* pidx  = (const int*)d_in[1];
    const float* Wq  = (const float*)d_in[3];
    const float* bq  = (const float*)d_in[4];
    const float* Wk  = (const float*)d_in[5];
    const float* bk  = (const float*)d_in[6];
    const float* Wv  = (const float*)d_in[7];
    const float* bv  = (const float*)d_in[8];
    const float* Wo  = (const float*)d_in[9];
    const float* bo  = (const float*)d_in[10];
    const float* lng = (const float*)d_in[11];
    const float* lnb = (const float*)d_in[12];

    // ws: qkv bf16 [P][S][768] (100.7MB)
    //   | region2 (25.2MB): xb bf16 [N][256] (k_pre,k_qkv) then att [P][192][256]
    //     (k_attn writes AFTER k_qkv's last read -- stream-ordered)
    //   | Wb bf16 [1024][256] (pre-swz) | bb f32 [768]
    unsigned short* qkv = (unsigned short*)d_ws;
    unsigned short* xb  = qkv + (size_t)PP * SS * 768;
    unsigned short* att = xb;                       // alias, reused after k_qkv
    unsigned short* Wb  = xb + (size_t)PP * CORE_ * HH;
    float* bb = (float*)(Wb + 1024 * 256);

    k_pre<<<6275, 256, 0, stream>>>(x, Wq, Wk, Wv, Wo, bq, bk, bv, xb, Wb, bb);
    k_qkv<<<dim3(PP, 2, 3), 256, 0, stream>>>(xb, pidx, Wb, bb, qkv);
    k_attn<<<dim3(PP, NHEAD), 256, 0, stream>>>(qkv, att);
    k_out<<<dim3(PP, 3), 256, 0, stream>>>(att, x, Wb, bo, lng, lnb, (float*)d_out);
}

// Round 20
// 133.420 us; speedup vs baseline: 1.2311x; 1.2311x over previous
//
#include <hip/hip_runtime.h>

#define PP 256
#define SS 256
#define CORE_ 192
#define HH 256
#define NHEAD 8
#define DD 32

typedef __attribute__((ext_vector_type(4))) float f32x4;
typedef __attribute__((ext_vector_type(8))) short s8v;
typedef __attribute__((ext_vector_type(4))) short s4v;

__device__ __forceinline__ unsigned short f2bf(float f) {
    union { float f; unsigned int i; } c; c.f = f;
    unsigned int i = c.i;
    return (unsigned short)((i + 0x7fffu + ((i >> 16) & 1u)) >> 16);
}

// async global->LDS 16B DMA; lds base must be wave-uniform (HW adds lane*16)
__device__ __forceinline__ void gload16(const unsigned short* g, unsigned short* l) {
    __builtin_amdgcn_global_load_lds(
        (const __attribute__((address_space(1))) void*)g,
        (__attribute__((address_space(3))) void*)l, 16, 0, 0);
}

// 16B-chunk XOR swizzle (involution) for [rows][32-short] tiles; 0-conflict (r3/r6).
#define SW(row, chunk) ((chunk) ^ (((row) >> 1) & 3))
// Vt swizzle (r12): 2-way on reads (d = nt*16+c0), 4-distinct on writes (d = dw*8+e)
#define SVT(d) ((((d) >> 1) & 3) ^ (((d) & 8) >> 1) ^ (((d) & 16) >> 3))

// ---------------- K0: fused pre-pass: x cast + weight/bias pack --------
__global__ __launch_bounds__(256) void k_pre(
    const float* __restrict__ x,
    const float* __restrict__ Wq, const float* __restrict__ Wk,
    const float* __restrict__ Wv, const float* __restrict__ Wo,
    const float* __restrict__ bq, const float* __restrict__ bk,
    const float* __restrict__ bv,
    unsigned short* __restrict__ xb,
    unsigned short* __restrict__ Wb, float* __restrict__ bb) {
    int bid = blockIdx.x, tid = threadIdx.x;
    if (bid < 6144) {
        size_t i = ((size_t)bid * 256 + tid) * 8;
        float4 a = *(const float4*)(x + i);
        float4 b = *(const float4*)(x + i + 4);
        s8v w;
        w[0] = (short)f2bf(a.x); w[1] = (short)f2bf(a.y);
        w[2] = (short)f2bf(a.z); w[3] = (short)f2bf(a.w);
        w[4] = (short)f2bf(b.x); w[5] = (short)f2bf(b.y);
        w[6] = (short)f2bf(b.z); w[7] = (short)f2bf(b.w);
        *(s8v*)(xb + i) = w;
        return;
    }
    if (bid >= 6272) {
        int which = bid - 6272;
        const float* b = which == 0 ? bq : which == 1 ? bk : bv;
        bb[which * 256 + tid] = b[tid];
        return;
    }
    int c = (bid - 6144) * 256 + tid;   // chunk 0..32767
    int row = c >> 5;                   // 0..1023
    int within = c & 31;
    int w = within >> 2, sl = within & 3;
    const float* src = row < 256 ? Wq : row < 512 ? Wk : row < 768 ? Wv : Wo;
    const float* sp = src + (size_t)(row & 255) * 256 + w * 32 + SW(row, sl) * 8;
    float4 a = *(const float4*)sp;
    float4 b4 = *(const float4*)(sp + 4);
    s8v wv;
    wv[0] = (short)f2bf(a.x); wv[1] = (short)f2bf(a.y);
    wv[2] = (short)f2bf(a.z); wv[3] = (short)f2bf(a.w);
    wv[4] = (short)f2bf(b4.x); wv[5] = (short)f2bf(b4.y);
    wv[6] = (short)f2bf(b4.z); wv[7] = (short)f2bf(b4.w);
    *(s8v*)(Wb + (size_t)row * 256 + w * 32 + sl * 8) = wv;
}

// ---------------- K1: QKV projection (r15 winner: 256 thr, BK=64) ------
__global__ __launch_bounds__(256) void k_qkv(
    const unsigned short* __restrict__ xb, const int* __restrict__ pidx,
    const unsigned short* __restrict__ Wb, const float* __restrict__ bb,
    unsigned short* __restrict__ qkv) {
    int p = blockIdx.x, mt = blockIdx.y, ng = blockIdx.z;
    if (ng == 0 && mt == 3) return;  // Q rows 192..255 never consumed
    __shared__ unsigned short As[2][64][32];
    __shared__ unsigned short Bs[2][256][32];
    int tid = threadIdx.x;
    int wave = tid >> 6, lane = tid & 63;
    int g = lane >> 4, c0 = lane & 15;
    f32x4 acc[4][4] = {};
    int arow = tid >> 2, aseg = tid & 3;
    int node = pidx[p * SS + mt * 64 + arow];
    const unsigned short* asrc = xb + (size_t)node * HH + aseg * 8;
    const unsigned short* wsrc = Wb + (size_t)ng * 256 * 256;

    s8v av0 = *(const s8v*)(asrc);
    s8v av1 = *(const s8v*)(asrc + 32);
#pragma unroll
    for (int ks = 0; ks < 4; ++ks) {
        int k0 = ks * 64;
#pragma unroll
        for (int kk = 0; kk < 2; ++kk)
#pragma unroll
            for (int j = 0; j < 4; ++j) {
                int chunk = j * 256 + wave * 64 + lane;
                int row = chunk >> 2, c8 = chunk & 3;
                gload16(wsrc + (size_t)row * 256 + k0 + kk * 32 + c8 * 8,
                        &Bs[kk][0][0] + (size_t)(j * 256 + wave * 64) * 8);
            }
        *(s8v*)&As[0][arow][SW(arow, aseg) * 8] = av0;
        *(s8v*)&As[1][arow][SW(arow, aseg) * 8] = av1;
        if (ks < 3) {
            av0 = *(const s8v*)(asrc + k0 + 64);
            av1 = *(const s8v*)(asrc + k0 + 96);
        }
        __syncthreads();
        s8v af[4][2], bfv[4][2];
#pragma unroll
        for (int m2 = 0; m2 < 4; ++m2) {
            int r = m2 * 16 + c0;
#pragma unroll
            for (int kk = 0; kk < 2; ++kk)
                af[m2][kk] = *(const s8v*)&As[kk][r][SW(r, g) * 8];
        }
#pragma unroll
        for (int nt = 0; nt < 4; ++nt) {
            int r = wave * 64 + nt * 16 + c0;
#pragma unroll
            for (int kk = 0; kk < 2; ++kk)
                bfv[nt][kk] = *(const s8v*)&Bs[kk][r][SW(r, g) * 8];
        }
#pragma unroll
        for (int m2 = 0; m2 < 4; ++m2)
#pragma unroll
            for (int nt = 0; nt < 4; ++nt) {
                acc[m2][nt] = __builtin_amdgcn_mfma_f32_16x16x32_bf16(
                    af[m2][0], bfv[nt][0], acc[m2][nt], 0, 0, 0);
                acc[m2][nt] = __builtin_amdgcn_mfma_f32_16x16x32_bf16(
                    af[m2][1], bfv[nt][1], acc[m2][nt], 0, 0, 0);
            }
        __syncthreads();
    }
    // epilogue: +bias; Q pre-scaled by log2(e)/sqrt(32); K stored swcol'd
    float sc = (ng == 0) ? 0.2550348792930095f : 1.0f;
#pragma unroll
    for (int nt = 0; nt < 4; ++nt) {
        int ncol = wave * 64 + nt * 16 + c0;
        float bv_ = bb[ng * 256 + ncol];
#pragma unroll
        for (int m2 = 0; m2 < 4; ++m2)
#pragma unroll
            for (int r = 0; r < 4; ++r) {
                int srow = mt * 64 + m2 * 16 + g * 4 + r;
                int sc_col = ncol;
                if (ng == 1) {  // store K chunk-swizzled so DMA+SW read works
                    sc_col = (ncol & ~31) |
                             ((((ncol >> 3) & 3) ^ ((srow >> 1) & 3)) << 3) |
                             (ncol & 7);
                }
                qkv[((size_t)p * SS + srow) * 768 + ng * 256 + sc_col] =
                    f2bf((acc[m2][nt][r] + bv_) * sc);
            }
    }
}

// ---------------- K2: attention (swapped QK^T, in-register P) + setprio -
__global__ __launch_bounds__(256) void k_attn(
    const unsigned short* __restrict__ qkv, unsigned short* __restrict__ att) {
    int p = blockIdx.x, h = blockIdx.y;
    __shared__ unsigned short Ks[256][32];
    __shared__ unsigned short Vt[32][256];
    int tid = threadIdx.x;
    int wave = tid >> 6, lane = tid & 63;
    int g = lane >> 4, c0 = lane & 15;

#pragma unroll
    for (int j = 0; j < 4; ++j) {
        int chunk = j * 256 + wave * 64 + lane;
        int row = chunk >> 2, c8 = chunk & 3;
        gload16(qkv + ((size_t)p * SS + row) * 768 + 256 + h * DD + c8 * 8,
                &Ks[0][0] + (size_t)(j * 256 + wave * 64) * 8);
    }
    {
        int dw = tid & 3, jb = tid >> 2;       // jb 0..63
        int j0 = jb * 4;
        const unsigned short* vbase =
            qkv + ((size_t)p * SS + j0) * 768 + 512 + h * DD + dw * 8;
        s8v r0 = *(const s8v*)(vbase);
        s8v r1 = *(const s8v*)(vbase + 768);
        s8v r2 = *(const s8v*)(vbase + 1536);
        s8v r3 = *(const s8v*)(vbase + 2304);
        int cj = (j0 >> 5) * 4 + ((j0 >> 2) & 3);   // slot chunk (0..31)
        int jo = ((j0 >> 4) & 1) * 4;               // offset within chunk {0,4}
#pragma unroll
        for (int e = 0; e < 8; ++e) {
            int d = dw * 8 + e;
            s4v w4;
            w4[0] = r0[e]; w4[1] = r1[e]; w4[2] = r2[e]; w4[3] = r3[e];
            *(s4v*)&Vt[d][((cj ^ SVT(d)) << 3) + jo] = w4;
        }
    }
    __syncthreads();

    for (int mi = 0; mi < 3; ++mi) {
        int q0 = (wave * 3 + mi) * 16;
        s8v qa = *(const s8v*)(qkv + ((size_t)p * SS + q0 + c0) * 768 + h * DD + g * 8);
        unsigned int plo[16], phi[16];
        float sum = 0.f;
        __builtin_amdgcn_s_setprio(1);     // favor this wave while MFMA-heavy
#pragma unroll
        for (int jt = 0; jt < 16; ++jt) {
            int row = jt * 16 + c0;
            s8v kf = *(const s8v*)&Ks[row][SW(row, g) * 8];
            f32x4 s = __builtin_amdgcn_mfma_f32_16x16x32_bf16(
                kf, qa, f32x4{0.f, 0.f, 0.f, 0.f}, 0, 0, 0);
            float e0 = exp2f(s[0]), e1 = exp2f(s[1]);
            float e2 = exp2f(s[2]), e3 = exp2f(s[3]);
            sum += (e0 + e1) + (e2 + e3);
            unsigned int lo, hi;
            asm("v_cvt_pk_bf16_f32 %0, %1, %2" : "=v"(lo) : "v"(e0), "v"(e1));
            asm("v_cvt_pk_bf16_f32 %0, %1, %2" : "=v"(hi) : "v"(e2), "v"(e3));
            plo[jt] = lo; phi[jt] = hi;
        }
        __builtin_amdgcn_s_setprio(0);
        sum += __shfl_xor(sum, 16, 64);
        sum += __shfl_xor(sum, 32, 64);
        float linv = 1.f / sum;        // for q = q0 + c0
        float lrow[4];
#pragma unroll
        for (int r = 0; r < 4; ++r) lrow[r] = __shfl(linv, g * 4 + r, 64);

        f32x4 oacc[2] = {f32x4{0.f, 0.f, 0.f, 0.f}, f32x4{0.f, 0.f, 0.f, 0.f}};
        __builtin_amdgcn_s_setprio(1);
#pragma unroll
        for (int ks = 0; ks < 8; ++ks) {
            union { unsigned int u[4]; s8v v; } pa;
            pa.u[0] = plo[2 * ks];     pa.u[1] = phi[2 * ks];
            pa.u[2] = plo[2 * ks + 1]; pa.u[3] = phi[2 * ks + 1];
#pragma unroll
            for (int nt = 0; nt < 2; ++nt) {
                int d = nt * 16 + c0;
                s8v vb = *(const s8v*)&Vt[d][(((ks * 4 + g) ^ SVT(d)) << 3)];
                oacc[nt] = __builtin_amdgcn_mfma_f32_16x16x32_bf16(
                    pa.v, vb, oacc[nt], 0, 0, 0);
            }
        }
        __builtin_amdgcn_s_setprio(0);
#pragma unroll
        for (int nt = 0; nt < 2; ++nt)
#pragma unroll
            for (int r = 0; r < 4; ++r) {
                int qq = g * 4 + r;
                att[((size_t)p * CORE_ + q0 + qq) * HH + h * DD + nt * 16 + c0] =
                    f2bf(oacc[nt][r] * lrow[r]);
            }
    }
}

// ---------------- K3: out-proj + residual + LayerNorm (r15, BK=64) -----
__global__ __launch_bounds__(256) void k_out(
    const unsigned short* __restrict__ att, const float* __restrict__ x,
    const unsigned short* __restrict__ Wb, const float* __restrict__ bo,
    const float* __restrict__ ln_g, const float* __restrict__ ln_b,
    float* __restrict__ out) {
    int p = blockIdx.x, mb = blockIdx.y;
    __shared__ unsigned short As[2][64][32];
    __shared__ unsigned short Bs[2][256][32];
    int tid = threadIdx.x;
    int wave = tid >> 6, lane = tid & 63;
    int g = lane >> 4, c0 = lane & 15;
    f32x4 acc[16] = {};
    int arow = tid >> 2, aseg = tid & 3;
    const unsigned short* asrc =
        att + ((size_t)p * CORE_ + mb * 64 + arow) * HH + aseg * 8;

    s8v av0 = *(const s8v*)(asrc);
    s8v av1 = *(const s8v*)(asrc + 32);
#pragma unroll
    for (int ks = 0; ks < 4; ++ks) {
        int k0 = ks * 64;
#pragma unroll
        for (int kk = 0; kk < 2; ++kk)
#pragma unroll
            for (int j = 0; j < 4; ++j) {
                int chunk = j * 256 + wave * 64 + lane;
                int row = chunk >> 2, c8 = chunk & 3;
                gload16(Wb + (size_t)(768 + row) * 256 + k0 + kk * 32 + c8 * 8,
                        &Bs[kk][0][0] + (size_t)(j * 256 + wave * 64) * 8);
            }
        *(s8v*)&As[0][arow][SW(arow, aseg) * 8] = av0;
        *(s8v*)&As[1][arow][SW(arow, aseg) * 8] = av1;
        if (ks < 3) {
            av0 = *(const s8v*)(asrc + k0 + 64);
            av1 = *(const s8v*)(asrc + k0 + 96);
        }
        __syncthreads();
        int ar = wave * 16 + c0;
        s8v af0 = *(const s8v*)&As[0][ar][SW(ar, g) * 8];
        s8v af1 = *(const s8v*)&As[1][ar][SW(ar, g) * 8];
#pragma unroll
        for (int nt = 0; nt < 16; ++nt) {
            int r = nt * 16 + c0;
            s8v b0 = *(const s8v*)&Bs[0][r][SW(r, g) * 8];
            s8v b1 = *(const s8v*)&Bs[1][r][SW(r, g) * 8];
            acc[nt] = __builtin_amdgcn_mfma_f32_16x16x32_bf16(af0, b0, acc[nt], 0, 0, 0);
            acc[nt] = __builtin_amdgcn_mfma_f32_16x16x32_bf16(af1, b1, acc[nt], 0, 0, 0);
        }
        __syncthreads();
    }
    int srow0 = mb * 64 + wave * 16 + g * 4;
    float sum[4] = {0, 0, 0, 0}, ssq[4] = {0, 0, 0, 0};
#pragma unroll
    for (int nt = 0; nt < 16; ++nt) {
        int col = nt * 16 + c0;
        float bov = bo[col];
#pragma unroll
        for (int r = 0; r < 4; ++r) {
            size_t node = (size_t)p * CORE_ + srow0 + r;
            float v = acc[nt][r] + bov + x[node * HH + col];
            acc[nt][r] = v;
            sum[r] += v; ssq[r] += v * v;
        }
    }
#pragma unroll
    for (int off = 1; off < 16; off <<= 1) {
#pragma unroll
        for (int r = 0; r < 4; ++r) {
            sum[r] += __shfl_xor(sum[r], off, 64);
            ssq[r] += __shfl_xor(ssq[r], off, 64);
        }
    }
#pragma unroll
    for (int r = 0; r < 4; ++r) {
        float mu = sum[r] * (1.f / HH);
        float var = ssq[r] * (1.f / HH) - mu * mu;
        float rstd = rsqrtf(var + 1e-5f);
        size_t node = (size_t)p * CORE_ + srow0 + r;
#pragma unroll
        for (int nt = 0; nt < 16; ++nt) {
            int col = nt * 16 + c0;
            out[node * HH + col] = (acc[nt][r] - mu) * rstd * ln_g[col] + ln_b[col];
        }
    }
}

extern "C" void kernel_launch(void* const* d_in, const int* in_sizes, int n_in,
                              void* d_out, int out_size, void* d_ws, size_t ws_size,
                              hipStream_t stream) {
    const float* x   = (const float*)d_in[0];
    const int* pidx  = (const int*)d_in[1];
    const float* Wq  = (const float*)d_in[3];
    const float* bq  = (const float*)d_in[4];
    const float* Wk  = (const float*)d_in[5];
    const float* bk  = (const float*)d_in[6];
    const float* Wv  = (const float*)d_in[7];
    const float* bv  = (const float*)d_in[8];
    const float* Wo  = (const float*)d_in[9];
    const float* bo  = (const float*)d_in[10];
    const float* lng = (const float*)d_in[11];
    const float* lnb = (const float*)d_in[12];

    // ws: qkv bf16 [P][S][768] (100.7MB)
    //   | region2 (25.2MB): xb bf16 [N][256] (k_pre,k_qkv) then att [P][192][256]
    //     (k_attn writes AFTER k_qkv's last read -- stream-ordered)
    //   | Wb bf16 [1024][256] (pre-swz) | bb f32 [768]
    unsigned short* qkv = (unsigned short*)d_ws;
    unsigned short* xb  = qkv + (size_t)PP * SS * 768;
    unsigned short* att = xb;                       // alias, reused after k_qkv
    unsigned short* Wb  = xb + (size_t)PP * CORE_ * HH;
    float* bb = (float*)(Wb + 1024 * 256);

    k_pre<<<6275, 256, 0, stream>>>(x, Wq, Wk, Wv, Wo, bq, bk, bv, xb, Wb, bb);
    k_qkv<<<dim3(PP, 4, 3), 256, 0, stream>>>(xb, pidx, Wb, bb, qkv);
    k_attn<<<dim3(PP, NHEAD), 256, 0, stream>>>(qkv, att);
    k_out<<<dim3(PP, 3), 256, 0, stream>>>(att, x, Wb, bo, lng, lnb, (float*)d_out);
}